// Round 7
// baseline (237.558 us; speedup 1.0000x reference)
//
#include <hip/hip_runtime.h>

#define BATCH 4
#define CCH   512
#define NN    4096
#define MIDD  64

typedef unsigned short u16;
typedef unsigned int   u32;
typedef short s8v  __attribute__((ext_vector_type(8)));
typedef float f16v __attribute__((ext_vector_type(16)));

__device__ __forceinline__ u16 f2bf(float f) {
  u32 u = __float_as_uint(f);
  u += 0x7fffu + ((u >> 16) & 1u);   // RTNE
  return (u16)(u >> 16);
}

// async global->LDS DMA, 16B per lane; dest = wave-uniform base + lane*16
__device__ __forceinline__ void g2lds16(const void* g, void* l) {
  __builtin_amdgcn_global_load_lds(
      (const __attribute__((address_space(1))) u32*)g,
      (__attribute__((address_space(3))) u32*)l, 16, 0, 0);
}

// s_waitcnt imm (gfx9): vmcnt [3:0]+[15:14], expcnt [6:4]=7, lgkmcnt [11:8]
#define S_WAITCNT(vm, lgkm) \
  __builtin_amdgcn_s_waitcnt(((vm) & 15) | (((vm) >> 4) << 14) | (0x7 << 4) | ((lgkm) << 8))

// ---------------------------------------------------------------------------
// prep_w: Wb[640][512] bf16 = [Wq; Wk; Wv] fp32 (once) + bb[640] = [bq;bk;bv].
// ---------------------------------------------------------------------------
__global__ __launch_bounds__(256) void prep_w(
    const float* __restrict__ Wq, const float* __restrict__ Wk,
    const float* __restrict__ Wv,
    const float* __restrict__ bq, const float* __restrict__ bk,
    const float* __restrict__ bv,
    u16* __restrict__ Wb, float* __restrict__ bb)
{
  const int bid = blockIdx.x;
  const int t   = threadIdx.x;
  if (bid < 160) {
    int e = (bid * 256 + t) * 8;
    const float* src;
    if (e < 64 * 512)       src = Wq + e;
    else if (e < 128 * 512) src = Wk + (e - 64 * 512);
    else                    src = Wv + (e - 128 * 512);
    float4 v0 = *(const float4*)src;
    float4 v1 = *(const float4*)(src + 4);
    uint4 p;
    p.x = (u32)f2bf(v0.x) | ((u32)f2bf(v0.y) << 16);
    p.y = (u32)f2bf(v0.z) | ((u32)f2bf(v0.w) << 16);
    p.z = (u32)f2bf(v1.x) | ((u32)f2bf(v1.y) << 16);
    p.w = (u32)f2bf(v1.z) | ((u32)f2bf(v1.w) << 16);
    *(uint4*)(Wb + e) = p;
  } else if (t < 160) {
    int e = t * 4;
    const float* s = (t < 16) ? (bq + e) : (t < 32) ? (bk + (e - 64)) : (bv + (e - 128));
    *(float4*)&bb[e] = *(const float4*)s;
  }
}

// ---------------------------------------------------------------------------
// proj_gemm v4: fused transpose + q/k/v projection (x consumed directly).
// Block: 128 m x 128 n, 4 waves (wave w: n-sub w*32, all 4 m-subs). BK=32.
// g = blockIdx.y: 0 -> Wq+Wk rows 0..127 (transpose epilogue -> qT/kT),
//                 1..4 -> Wv slab rows 128g..128g+127 (natural -> vT).
// Per chunk: DMA x [32c][128n] fp32 into LDS (conflict-free), VALU
// transpose/cvt -> bf16 B-tile [128n][32c] (4-blk xor n&3 swizzle),
// W chunk DMA'd from prepped Wb. 32 KB LDS.
// ---------------------------------------------------------------------------
__global__ __launch_bounds__(256, 2) void proj_gemm(
    const float* __restrict__ x, const u16* __restrict__ Wb,
    const float* __restrict__ bb,
    u16* __restrict__ qT, u16* __restrict__ kT, u16* __restrict__ vT)
{
  __shared__ char smem[32768];
  float* xf  = (float*)smem;            // [32][128] fp32 staging
  u16*   xb  = (u16*)(smem + 16384);    // [128][32] bf16 B-tile, swizzled
  u16*   wsm = (u16*)(smem + 24576);    // [128][32] bf16 A-tile, swizzled

  const int b     = blockIdx.z;
  const int g     = blockIdx.y;
  const int gn0   = blockIdx.x * 128;
  const int mrow0 = g * 128;
  const int t  = threadIdx.x;
  const int l  = t & 63, ln = l & 31, hi = l >> 5, w = t >> 6;

  // xf DMA: instr i covers rows {w*8+2i, +1}; lane l -> row +(l>>5), col (l&31)*4
  const float* xsrc = x + ((size_t)(b * CCH) + w * 8 + (l >> 5)) * NN + gn0 + (l & 31) * 4;
  // wsm DMA: instr i covers rows w*32+i*16+(l>>2); swizzled col block (l&3)^((l>>2)&3)
  const u16* wsrc = Wb + (size_t)(mrow0 + w * 32 + (l >> 2)) * 512 + ((l & 3) ^ ((l >> 2) & 3)) * 8;

  f16v acc[4];
  #pragma unroll
  for (int i = 0; i < 4; i++)
    #pragma unroll
    for (int r = 0; r < 16; r++) acc[i][r] = 0.f;

  const int nrow = t >> 1, ch = (t & 1) * 16;   // transpose-pass ownership

  for (int it = 0; it < 16; it++) {
    const int c0 = it * 32;
    __syncthreads();                    // prev chunk frag/transpose reads done
    #pragma unroll
    for (int i = 0; i < 4; i++)
      g2lds16(xsrc + (size_t)(c0 + 2 * i) * NN, xf + (w * 8 + 2 * i) * 128);
    #pragma unroll
    for (int i = 0; i < 2; i++)
      g2lds16(wsrc + (size_t)(i * 16) * 512 + c0, wsm + (w * 32 + i * 16) * 32);
    __syncthreads();                    // staged visible (vmcnt drained)

    // transpose + cvt: thread owns col n=nrow, c-range [ch, ch+16)
    u32 pk[8];
    #pragma unroll
    for (int j2 = 0; j2 < 8; j2++) {
      float f0 = xf[(ch + 2 * j2 + 0) * 128 + nrow];
      float f1 = xf[(ch + 2 * j2 + 1) * 128 + nrow];
      pk[j2] = (u32)f2bf(f0) | ((u32)f2bf(f1) << 16);
    }
    #pragma unroll
    for (int p2 = 0; p2 < 2; p2++) {
      int phys = ((ch >> 3) + p2) ^ (nrow & 3);
      *(uint4*)&xb[(nrow << 5) + (phys << 3)] =
          make_uint4(pk[p2 * 4], pk[p2 * 4 + 1], pk[p2 * 4 + 2], pk[p2 * 4 + 3]);
    }
    __syncthreads();                    // xb visible

    #pragma unroll
    for (int ks = 0; ks < 2; ks++) {
      const int cb = ((2 * ks + hi) ^ (ln & 3)) << 3;
      s8v bf = *(const s8v*)&xb[((w * 32 + ln) << 5) + cb];
      #pragma unroll
      for (int ms = 0; ms < 4; ms++) {
        s8v af = *(const s8v*)&wsm[((ms * 32 + ln) << 5) + cb];
        acc[ms] = __builtin_amdgcn_mfma_f32_32x32x16_bf16(af, bf, acc[ms], 0, 0, 0);
      }
    }
  }
  __syncthreads();                      // all frag reads done before LDS reuse

  if (g > 0) {
    // natural [m][n] epilogue -> vT (d = W row - 128)
    const int d0 = mrow0 - 128;
    #pragma unroll
    for (int ms = 0; ms < 4; ms++)
      #pragma unroll
      for (int r = 0; r < 16; r++) {
        int m = ms * 32 + (r & 3) + 8 * (r >> 2) + 4 * hi;
        float val = acc[ms][r] + bb[mrow0 + m];
        vT[((size_t)b * CCH + d0 + m) * NN + gn0 + w * 32 + ln] = f2bf(val);
      }
  } else {
    // transpose epilogue: scratch [128n][128m] u16, 16-blk xor (n&15) swizzle
    u16* scr = (u16*)smem;
    const int n = w * 32 + ln;
    #pragma unroll
    for (int ms = 0; ms < 4; ms++)
      #pragma unroll
      for (int r2 = 0; r2 < 8; r2++) {
        int r = 2 * r2;
        int m = ms * 32 + (r & 3) + 8 * (r >> 2) + 4 * hi;   // even; m+1 same 8-blk
        u32 p = (u32)f2bf(acc[ms][r] + bb[m]) |
                ((u32)f2bf(acc[ms][r + 1] + bb[m + 1]) << 16);
        *(u32*)&scr[(n << 7) + ((((m >> 3) ^ (n & 15))) << 3) + (m & 7)] = p;
      }
    __syncthreads();
    const int nr = t >> 1, half = t & 1;
    u16* drow = (half ? kT : qT) + ((size_t)b * NN + gn0 + nr) * 64;
    #pragma unroll
    for (int k = 0; k < 8; k++) {
      int phys = (half * 8 + k) ^ (nr & 15);
      *(uint4*)&drow[k * 8] = *(const uint4*)&scr[(nr << 7) + (phys << 3)];
    }
  }
}

// ---------------------------------------------------------------------------
// MFMA flash attention v3 (unchanged from R5/R6; kept for attribution).
// ---------------------------------------------------------------------------
__global__ __launch_bounds__(256, 2) void attn_kernel(
    const u16* __restrict__ qT,   // [B][N][64] bf16
    const u16* __restrict__ kT,   // [B][N][64] bf16
    const u16* __restrict__ vT,   // [B][C][N] bf16
    const float* __restrict__ x,  // [B][C][N] fp32
    const float* __restrict__ gamma,
    float* __restrict__ out)      // [B][C][N] fp32
{
  __shared__ u16 ksm[2][64 * 64];   // K tiles [j][m], swizzled
  __shared__ u16 plm[2][64 * 64];   // P tiles [q][j], swizzled
  __shared__ u16 vsm[256 * 64];     // V tile [d][j], swizzled

  const int bx    = blockIdx.x;
  const int slot  = bx & 7;
  const int b     = slot >> 1;
  const int dbase = (slot & 1) * 256;
  const int i0    = (bx >> 3) * 64;
  const int t     = threadIdx.x;
  const int l     = t & 63, ln = l & 31, hi = l >> 5;
  const int w     = t >> 6;
  const int qh    = w >> 1;
  const int jh    = w & 1;
  const int l3    = l & 7, lh3 = l >> 3;
  const int sw8   = (l3 ^ lh3) * 8;

  s8v qfrag[4];
  {
    const u16* qp = qT + ((size_t)b * NN + i0 + qh * 32 + ln) * 64 + hi * 8;
    #pragma unroll
    for (int k = 0; k < 4; k++) qfrag[k] = *(const s8v*)(qp + 16 * k);
  }

  const u16* kbase = kT + (size_t)b * NN * 64;
  const u16* vbase = vT + ((size_t)b * CCH + dbase) * NN;
  const u16* ksrc  = kbase + (size_t)(16 * w + lh3) * 64 + sw8;
  const u16* vsrc  = vbase + (size_t)(64 * w + lh3) * NN + sw8;

  f16v oacc[4];                    // [ds][qt]
  #pragma unroll
  for (int i = 0; i < 4; i++)
    #pragma unroll
    for (int r = 0; r < 16; r++) oacc[i][r] = 0.f;
  float lpart[16];
  #pragma unroll
  for (int r = 0; r < 16; r++) lpart[r] = 0.f;

  #pragma unroll
  for (int i = 0; i < 2; i++)
    g2lds16(ksrc + (size_t)(8 * i) * 64, &ksm[0][(w * 2 + i) * 512]);

  for (int it = 0; it < 64; it++) {
    const int j0  = it * 64;
    const int cur = it & 1, nxt = cur ^ 1;

    __builtin_amdgcn_s_barrier();          // A: PV(i-1) done
    #pragma unroll
    for (int i = 0; i < 8; i++)
      g2lds16(vsrc + (size_t)(8 * i) * NN + j0, vsm + (w * 8 + i) * 512);
    const int j1 = ((it + 1) & 63) * 64;
    #pragma unroll
    for (int i = 0; i < 2; i++)
      g2lds16(ksrc + (size_t)(j1 + 8 * i) * 64, &ksm[nxt][(w * 2 + i) * 512]);

    S_WAITCNT(10, 15);                     // K(it) landed
    __builtin_amdgcn_s_barrier();          // B

    f16v sacc;
    #pragma unroll
    for (int r = 0; r < 16; r++) sacc[r] = 0.f;
    #pragma unroll
    for (int ks = 0; ks < 4; ks++) {
      s8v bf = *(const s8v*)&ksm[cur][(jh * 32 + ln) * 64 + (((2 * ks + hi) ^ l3) << 3)];
      sacc = __builtin_amdgcn_mfma_f32_32x32x16_bf16(qfrag[ks], bf, sacc, 0, 0, 0);
    }
    #pragma unroll
    for (int r = 0; r < 16; r++) {
      float p = __expf(sacc[r]);
      lpart[r] += p;
      int row = qh * 32 + (r & 3) + ((r >> 2) << 3) + (hi << 2);
      int r7  = (r & 3) + (hi << 2);
      int jbl = (jh << 2) + (ln >> 3);
      plm[cur][(row << 6) + ((jbl ^ r7) << 3) + (ln & 7)] = f2bf(p);
    }

    S_WAITCNT(2, 0);                       // V(it) landed + P flushed
    __builtin_amdgcn_s_barrier();          // C

    #pragma unroll
    for (int ks = 0; ks < 4; ks++) {
      const int cb = ((2 * ks + hi) ^ l3) << 3;
      s8v p0 = *(const s8v*)&plm[cur][(ln << 6) + cb];
      s8v p1 = *(const s8v*)&plm[cur][((32 + ln) << 6) + cb];
      s8v v0 = *(const s8v*)&vsm[(((w << 5) + ln) << 6) + cb];
      s8v v1 = *(const s8v*)&vsm[((((w + 4) << 5) + ln) << 6) + cb];
      oacc[0] = __builtin_amdgcn_mfma_f32_32x32x16_bf16(v0, p0, oacc[0], 0, 0, 0);
      oacc[1] = __builtin_amdgcn_mfma_f32_32x32x16_bf16(v0, p1, oacc[1], 0, 0, 0);
      oacc[2] = __builtin_amdgcn_mfma_f32_32x32x16_bf16(v1, p0, oacc[2], 0, 0, 0);
      oacc[3] = __builtin_amdgcn_mfma_f32_32x32x16_bf16(v1, p1, oacc[3], 0, 0, 0);
    }
  }

  S_WAITCNT(0, 0);
  __builtin_amdgcn_s_barrier();

  float* lred = (float*)&ksm[0][0];   // [2][64]
  #pragma unroll
  for (int r = 0; r < 16; r++) {
    float v = lpart[r];
    v += __shfl_xor(v, 1);  v += __shfl_xor(v, 2);  v += __shfl_xor(v, 4);
    v += __shfl_xor(v, 8);  v += __shfl_xor(v, 16);
    lpart[r] = v;
  }
  if (ln == 0) {
    #pragma unroll
    for (int r = 0; r < 16; r++) {
      int row = qh * 32 + (r & 3) + ((r >> 2) << 3) + (hi << 2);
      lred[jh * 64 + row] = lpart[r];
    }
  }
  __syncthreads();

  const float g0 = gamma[0];
  #pragma unroll
  for (int qt = 0; qt < 2; qt++) {
    const float linv = 1.0f / (lred[qt * 32 + ln] + lred[64 + qt * 32 + ln]);
    const int n = i0 + qt * 32 + ln;
    #pragma unroll
    for (int ds = 0; ds < 2; ds++) {
      f16v& a = oacc[ds * 2 + qt];
      const int dg = dbase + (w + 4 * ds) * 32;
      #pragma unroll
      for (int r = 0; r < 16; r++) {
        int dl = (r & 3) + 8 * (r >> 2) + 4 * hi;
        size_t idx = ((size_t)b * CCH + dg + dl) * NN + n;
        out[idx] = g0 * a[r] * linv + x[idx];
      }
    }
  }
}

// ---------------------------------------------------------------------------
extern "C" void kernel_launch(void* const* d_in, const int* in_sizes, int n_in,
                              void* d_out, int out_size, void* d_ws, size_t ws_size,
                              hipStream_t stream) {
  const float* x     = (const float*)d_in[0];
  const float* Wq    = (const float*)d_in[1];
  const float* bq    = (const float*)d_in[2];
  const float* Wk    = (const float*)d_in[3];
  const float* bk    = (const float*)d_in[4];
  const float* Wv    = (const float*)d_in[5];
  const float* bv    = (const float*)d_in[6];
  const float* gamma = (const float*)d_in[7];
  float* out = (float*)d_out;

  u16*   qT = (u16*)d_ws;                          // [B][N][64]   2 MB
  u16*   kT = qT + (size_t)BATCH * NN * MIDD;      // [B][N][64]   2 MB
  u16*   vT = kT + (size_t)BATCH * NN * MIDD;      // [B][C][N]   16.8 MB
  u16*   Wb = vT + (size_t)BATCH * CCH * NN;       // [640][512]   0.66 MB
  float* bb = (float*)(Wb + (size_t)640 * 512);    // [640]

  prep_w<<<dim3(161), 256, 0, stream>>>(Wq, Wk, Wv, bq, bk, bv, Wb, bb);
  proj_gemm<<<dim3(NN / 128, 5, BATCH), 256, 0, stream>>>(x, Wb, bb, qT, kT, vT);
  attn_kernel<<<dim3(512), 256, 0, stream>>>(qT, kT, vT, x, gamma, out);
}